// Round 9
// baseline (487.621 us; speedup 1.0000x reference)
//
#include <hip/hip_runtime.h>
#include <hip/hip_bf16.h>
#include <cstdint>
#include <cstddef>

// Problem constants
#define BB   512
#define NN   100
#define HH   768
#define II   1536
#define MM   (BB*NN)          // 51200 rows

typedef __bf16 bf16;
typedef __bf16 bf16x4 __attribute__((ext_vector_type(4)));
typedef __bf16 bf16x8 __attribute__((ext_vector_type(8)));
typedef float  f32x4  __attribute__((ext_vector_type(4)));

// async global -> LDS, 16B per lane (wave-uniform LDS base + lane*16)
__device__ __forceinline__ void gld_lds16(const void* g, void* l) {
    __builtin_amdgcn_global_load_lds(
        (const __attribute__((address_space(1))) void*)g,
        (__attribute__((address_space(3))) void*)l, 16, 0, 0);
}

// butterfly add over 16-lane groups via ds_swizzle (BitMode, single DS inst)
template <int PAT>
__device__ __forceinline__ float swz_add(float x) {
    return x + __int_as_float(
        __builtin_amdgcn_ds_swizzle(__float_as_int(x), PAT));
}
__device__ __forceinline__ float red16(float x) {
    x = swz_add<0x041F>(x);   // xor 1
    x = swz_add<0x081F>(x);   // xor 2
    x = swz_add<0x101F>(x);   // xor 4
    x = swz_add<0x201F>(x);   // xor 8
    return x;                 // all 16 lanes hold the group sum
}

// Fast exact-GELU: erf via Abramowitz-Stegun 7.1.26 (|err| <= 1.5e-7)
__device__ __forceinline__ float fast_gelu(float x) {
    const float ax = fabsf(x) * 0.70710678118654752f;   // |x|/sqrt(2)
    const float t  = __builtin_amdgcn_rcpf(fmaf(0.3275911f, ax, 1.0f));
    float p = fmaf(1.061405429f, t, -1.453152027f);
    p = fmaf(p, t, 1.421413741f);
    p = fmaf(p, t, -0.284496736f);
    p = fmaf(p, t, 0.254829592f);
    p = p * t;
    const float e    = __expf(-ax * ax);
    const float erfa = fmaf(-p, e, 1.0f);               // erf(|x|/sqrt2)
    const float erfx = copysignf(erfa, x);
    return 0.5f * x * (1.0f + erfx);
}

// ---------------------------------------------------------------------------
// prep: W1 fp32 [768][1536] -> Wp bf16 [1536][768] via LDS tile transpose;
//       gw = gamma*W2; scal = {S1, S2}.  (No A-pack: net-negative, R8.)
// ---------------------------------------------------------------------------
__global__ __launch_bounds__(256) void prep_kernel(
    const float* __restrict__ W1, const float* __restrict__ gamma,
    const float* __restrict__ beta, const float* __restrict__ W2,
    const float* __restrict__ b2,
    bf16* __restrict__ Wp, float* __restrict__ gw, float* __restrict__ scal)
{
    const int bid = blockIdx.x, tid = threadIdx.x;
    if (bid < 288) {
        __shared__ bf16 Ts[64 * 72];     // 64n x 64k, pad 8
        const int kt = bid % 12, nt = bid / 12;
        const int k0 = kt * 64, n0 = nt * 64;
        #pragma unroll
        for (int it = 0; it < 4; ++it) {
            const int idx = it * 256 + tid;          // 0..1023
            const int r   = idx >> 4;                // k-row 0..63
            const int c4  = idx & 15;                // n float4 0..15
            float4 v = *(const float4*)&W1[(size_t)(k0 + r) * II + n0 + c4*4];
            Ts[(c4*4 + 0) * 72 + r] = (bf16)v.x;
            Ts[(c4*4 + 1) * 72 + r] = (bf16)v.y;
            Ts[(c4*4 + 2) * 72 + r] = (bf16)v.z;
            Ts[(c4*4 + 3) * 72 + r] = (bf16)v.w;
        }
        __syncthreads();
        #pragma unroll
        for (int it = 0; it < 2; ++it) {
            const int idx = it * 256 + tid;          // 0..511
            const int nr  = idx >> 3;                // n-row 0..63
            const int kc  = idx & 7;                 // k-octet 0..7
            *(bf16x8*)&Wp[(size_t)(n0 + nr) * HH + k0 + kc*8]
                = *(const bf16x8*)&Ts[nr * 72 + kc*8];
        }
    } else if (bid == 288) {
        for (int j = tid; j < II; j += 256)
            gw[j] = gamma[j] * W2[j];
    } else {
        float s1 = 0.f, s2 = 0.f;
        for (int j = tid; j < II; j += 256) {
            float w2 = W2[j];
            s1 += gamma[j] * w2;
            s2 += beta[j]  * w2;
        }
        #pragma unroll
        for (int off = 32; off; off >>= 1) {
            s1 += __shfl_down(s1, off, 64);
            s2 += __shfl_down(s2, off, 64);
        }
        __shared__ float a1[4], a2[4];
        int lane = tid & 63, w = tid >> 6;
        if (lane == 0) { a1[w] = s1; a2[w] = s2; }
        __syncthreads();
        if (tid == 0) {
            scal[0] = a1[0] + a1[1] + a1[2] + a1[3];
            scal[1] = a2[0] + a2[1] + a2[2] + a2[3] + b2[0];
        }
    }
}

// ---------------------------------------------------------------------------
// gemm_part: 128x128 tile, BK=64, 16x16x32 bf16 MFMA.
// A read DIRECTLY from fp32 v_emb with a REGISTER-PREFETCH pipeline:
//   loads for tile kt+1 issue right after barrier-1 of tile kt and are
//   consumed (cvt + ds_write_b128) at the top of tile kt+1 — a full MFMA
//   phase (~1800 cyc) hides the latency. B stays async via global_load_lds.
// LDS layout (both tiles): row r, slot g holds k-group g^(r&7) -> lane*16
// staging contiguity AND <=2-way ds_read_b128 conflicts (free).
// sred aliased onto dead As. XCD swizzle: 12 nb-blocks per A-tile on 1 XCD.
// Epilogue: +b1, fast GELU, per-row partial LN stats -> part[s][nb][row].
// ---------------------------------------------------------------------------
__global__ __launch_bounds__(256) void gemm_part(
    const float* __restrict__ Af, const bf16* __restrict__ Wp,
    const float* __restrict__ b1, const float* __restrict__ gw,
    float* __restrict__ part)
{
    __shared__ bf16 As[128 * 64];      // 16 KB
    __shared__ bf16 Bs[128 * 64];      // 16 KB

    const int tid  = threadIdx.x;
    // XCD swizzle: 4800 blocks = 8 XCDs x 600; 600 = 50 mb x 12 nb
    const int lin  = (blockIdx.x % 8) * 600 + blockIdx.x / 8;
    const int mb   = lin / 12;
    const int nb   = lin % 12;
    const int lane = tid & 63;
    const int w    = tid >> 6;
    const int wm   = w >> 1;            // 0..1
    const int wn   = w & 1;             // 0..1
    const int m15  = lane & 15;
    const int q    = lane >> 4;         // 0..3
    const int row0 = mb * 128;

    // staging: thread covers row rsub=tid>>3, slot tid&7; slot g holds
    // k-group kg=g^(rsub&7)
    const int rsub  = tid >> 3;                   // 0..31
    const int kg    = (tid & 7) ^ (rsub & 7);
    const int lbase = tid * 8;

    const float* aP = Af + (size_t)(row0    + rsub) * HH + kg * 8;
    const bf16*  bP = Wp + (size_t)(nb*128 + rsub) * HH + kg * 8;

    // prologue: prefetch A registers for kt=0
    float4 av[4][2];
    #pragma unroll
    for (int it = 0; it < 4; ++it) {
        const float* s = aP + (size_t)it * 32 * HH;
        av[it][0] = *(const float4*)s;
        av[it][1] = *(const float4*)(s + 4);
    }

    f32x4 acc[4][4] = {};

    for (int kt = 0; kt < 12; ++kt) {
        // B: async global->LDS for this tile
        #pragma unroll
        for (int it = 0; it < 4; ++it)
            gld_lds16(bP + (size_t)it * 32 * HH, &Bs[lbase + it * 2048]);
        // A: consume prefetched registers (loaded a full MFMA phase ago)
        #pragma unroll
        for (int it = 0; it < 4; ++it) {
            const float4 v0 = av[it][0], v1 = av[it][1];
            bf16x8 o = { (bf16)v0.x, (bf16)v0.y, (bf16)v0.z, (bf16)v0.w,
                         (bf16)v1.x, (bf16)v1.y, (bf16)v1.z, (bf16)v1.w };
            *(bf16x8*)&As[lbase + it * 2048] = o;
        }
        asm volatile("s_waitcnt vmcnt(0)" ::: "memory");
        __syncthreads();

        // prefetch A for kt+1 (overlaps the MFMA phase below)
        aP += 64;
        if (kt < 11) {
            #pragma unroll
            for (int it = 0; it < 4; ++it) {
                const float* s = aP + (size_t)it * 32 * HH;
                av[it][0] = *(const float4*)s;
                av[it][1] = *(const float4*)(s + 4);
            }
        }

        #pragma unroll
        for (int kb = 0; kb < 2; ++kb) {
            const int swz = (((kb * 4 + q) ^ (m15 & 7)) * 8);
            bf16x8 af[4], bfr[4];
            #pragma unroll
            for (int mt = 0; mt < 4; ++mt)
                af[mt] = *(const bf16x8*)&As[(wm*64 + mt*16 + m15) * 64 + swz];
            #pragma unroll
            for (int nt = 0; nt < 4; ++nt)
                bfr[nt] = *(const bf16x8*)&Bs[(wn*64 + nt*16 + m15) * 64 + swz];
            #pragma unroll
            for (int mt = 0; mt < 4; ++mt)
                #pragma unroll
                for (int nt = 0; nt < 4; ++nt)
                    acc[mt][nt] = __builtin_amdgcn_mfma_f32_16x16x32_bf16(
                        af[mt], bfr[nt], acc[mt][nt], 0, 0, 0);
        }
        __syncthreads();
        bP += 64;
    }

    // epilogue: +b1, fast GELU, per-row partial stats over this block's cols
    float* sred = (float*)As;    // As dead after final barrier; 3 KB reuse

    float bv[4], gv[4];
    #pragma unroll
    for (int nt = 0; nt < 4; ++nt) {
        const int col = nb*128 + wn*64 + nt*16 + m15;
        bv[nt] = b1[col];
        gv[nt] = gw[col];
    }

    #pragma unroll
    for (int mt = 0; mt < 4; ++mt) {
        #pragma unroll
        for (int r = 0; r < 4; ++r) {
            float x0 = 0.f, x1 = 0.f, x2 = 0.f;
            #pragma unroll
            for (int nt = 0; nt < 4; ++nt) {
                // C/D layout: col = lane&15, row = q*4 + r
                float g = fast_gelu(acc[mt][nt][r] + bv[nt]);
                x0 += g; x1 += g * g; x2 += g * gv[nt];
            }
            x0 = red16(x0); x1 = red16(x1); x2 = red16(x2);
            if (m15 == 0) {
                const int rl = wm*64 + mt*16 + q*4 + r;   // 0..127
                sred[wn*384 + rl*3 + 0] = x0;
                sred[wn*384 + rl*3 + 1] = x1;
                sred[wn*384 + rl*3 + 2] = x2;
            }
        }
    }
    __syncthreads();

    if (tid < 128) {
        const size_t rg = (size_t)row0 + tid;
        #pragma unroll
        for (int s = 0; s < 3; ++s)
            part[(size_t)s * 12 * MM + (size_t)nb * MM + rg]
                = sred[0*384 + tid*3 + s] + sred[1*384 + tid*3 + s];
    }
}

// ---------------------------------------------------------------------------
// score_pred: finish LN + sigmoid for the 100 rows of batch b, write scores,
// then pred = sum(scores), logits = one_hot(clamp(round(pred),0,15))
// ---------------------------------------------------------------------------
__global__ __launch_bounds__(128) void score_pred(
    const float* __restrict__ part, const float* __restrict__ scal,
    float* __restrict__ o_scores, float* __restrict__ o_pred,
    float* __restrict__ o_logits)
{
    const int b = blockIdx.x, t = threadIdx.x;
    float s = 0.f;
    if (t < NN) {
        const size_t row = (size_t)b * NN + t;
        float Sh = 0.f, Shh = 0.f, Shg = 0.f;
        #pragma unroll
        for (int j = 0; j < 12; ++j) {
            Sh  += part[(size_t)0*12*MM + (size_t)j*MM + row];
            Shh += part[(size_t)1*12*MM + (size_t)j*MM + row];
            Shg += part[(size_t)2*12*MM + (size_t)j*MM + row];
        }
        const float mu   = Sh * (1.0f / II);
        const float var  = Shh * (1.0f / II) - mu * mu;
        const float rstd = rsqrtf(var + 1e-5f);
        const float z    = rstd * (Shg - mu * scal[0]) + scal[1];
        s = 1.0f / (1.0f + __expf(-z));
        o_scores[row] = s;
    }
    float v = s;
    #pragma unroll
    for (int off = 32; off; off >>= 1) v += __shfl_down(v, off, 64);
    __shared__ float ssum[2];
    const int lane = t & 63, w = t >> 6;
    if (lane == 0) ssum[w] = v;
    __syncthreads();
    const float p = ssum[0] + ssum[1];
    if (t == 0) o_pred[b] = p;
    if (t < 16) {
        int aid = (int)rintf(p);
        aid = aid < 0 ? 0 : (aid > 15 ? 15 : aid);
        o_logits[b * 16 + t] = (t == aid) ? 1.0f : 0.0f;
    }
}

// ---------------------------------------------------------------------------
extern "C" void kernel_launch(void* const* d_in, const int* in_sizes, int n_in,
                              void* d_out, int out_size, void* d_ws, size_t ws_size,
                              hipStream_t stream)
{
    const float* v_emb = (const float*)d_in[0];
    const float* W1    = (const float*)d_in[1];
    const float* b1    = (const float*)d_in[2];
    const float* gamma = (const float*)d_in[3];
    const float* beta  = (const float*)d_in[4];
    const float* W2    = (const float*)d_in[5];
    const float* b2    = (const float*)d_in[6];

    char* ws = (char*)d_ws;
    size_t off = 0;
    bf16*  Wp   = (bf16*)(ws + off);  off += (size_t)II * HH * 2;      // 2.36 MB
    float* gw   = (float*)(ws + off); off += (size_t)II * 4;
    float* scal = (float*)(ws + off); off += 256;
    float* part = (float*)(ws + off); off += (size_t)MM * 36 * 4;      // 7.37 MB

    float* out       = (float*)d_out;
    float* o_scores  = out;            // 51200
    float* o_pred    = out + MM;       // 512
    float* o_logits  = out + MM + BB;  // 8192

    hipLaunchKernelGGL(prep_kernel, dim3(290), dim3(256), 0, stream,
                       W1, gamma, beta, W2, b2, Wp, gw, scal);
    hipLaunchKernelGGL(gemm_part, dim3((MM / 128) * 12), dim3(256),
                       0, stream, v_emb, Wp, b1, gw, part);
    hipLaunchKernelGGL(score_pred, dim3(BB), dim3(128), 0, stream,
                       part, scal, o_scores, o_pred, o_logits);
}

// Round 10
// 438.890 us; speedup vs baseline: 1.1110x; 1.1110x over previous
//
#include <hip/hip_runtime.h>
#include <hip/hip_bf16.h>
#include <cstdint>
#include <cstddef>

// Problem constants
#define BB   512
#define NN   100
#define HH   768
#define II   1536
#define MM   (BB*NN)          // 51200 rows

typedef __bf16 bf16;
typedef __bf16 bf16x4 __attribute__((ext_vector_type(4)));
typedef __bf16 bf16x8 __attribute__((ext_vector_type(8)));
typedef float  f32x4  __attribute__((ext_vector_type(4)));

// async global -> LDS, 16B per lane (wave-uniform LDS base + lane*16)
__device__ __forceinline__ void gld_lds16(const void* g, void* l) {
    __builtin_amdgcn_global_load_lds(
        (const __attribute__((address_space(1))) void*)g,
        (__attribute__((address_space(3))) void*)l, 16, 0, 0);
}

// butterfly add over 16-lane groups via ds_swizzle (BitMode, single DS inst)
template <int PAT>
__device__ __forceinline__ float swz_add(float x) {
    return x + __int_as_float(
        __builtin_amdgcn_ds_swizzle(__float_as_int(x), PAT));
}
__device__ __forceinline__ float red16(float x) {
    x = swz_add<0x041F>(x);   // xor 1
    x = swz_add<0x081F>(x);   // xor 2
    x = swz_add<0x101F>(x);   // xor 4
    x = swz_add<0x201F>(x);   // xor 8
    return x;                 // all 16 lanes hold the group sum
}

// Fast exact-GELU: erf via Abramowitz-Stegun 7.1.26 (|err| <= 1.5e-7)
__device__ __forceinline__ float fast_gelu(float x) {
    const float ax = fabsf(x) * 0.70710678118654752f;   // |x|/sqrt(2)
    const float t  = __builtin_amdgcn_rcpf(fmaf(0.3275911f, ax, 1.0f));
    float p = fmaf(1.061405429f, t, -1.453152027f);
    p = fmaf(p, t, 1.421413741f);
    p = fmaf(p, t, -0.284496736f);
    p = fmaf(p, t, 0.254829592f);
    p = p * t;
    const float e    = __expf(-ax * ax);
    const float erfa = fmaf(-p, e, 1.0f);               // erf(|x|/sqrt2)
    const float erfx = copysignf(erfa, x);
    return 0.5f * x * (1.0f + erfx);
}

// ---------------------------------------------------------------------------
// prep: one launch does everything the gemm needs:
//   bid <  288 : W1 fp32 [768][1536] -> Wp bf16 [1536][768] (LDS transpose)
//   bid == 288 : gw = gamma*W2
//   bid == 289 : scal = {S1 = sum gamma*W2, S2 = sum beta*W2 + b2}
//   bid >= 290 : pack v_emb fp32 -> Apk bf16 (4800 blocks, 16B b128 stores)
// ---------------------------------------------------------------------------
__global__ __launch_bounds__(256) void prep_kernel(
    const float* __restrict__ W1, const float* __restrict__ gamma,
    const float* __restrict__ beta, const float* __restrict__ W2,
    const float* __restrict__ b2, const float* __restrict__ A,
    bf16* __restrict__ Wp, float* __restrict__ gw, float* __restrict__ scal,
    bf16* __restrict__ Apk)
{
    const int bid = blockIdx.x, tid = threadIdx.x;
    if (bid >= 290) {
        // A-pack: 4800 blocks x 4 iters x 256 threads x 8 elems
        const size_t base = (size_t)(bid - 290) * 8192 + tid * 8;
        #pragma unroll
        for (int it = 0; it < 4; ++it) {
            const size_t i = base + it * 2048;
            float4 v0 = *(const float4*)&A[i];
            float4 v1 = *(const float4*)&A[i + 4];
            bf16x8 o = { (bf16)v0.x, (bf16)v0.y, (bf16)v0.z, (bf16)v0.w,
                         (bf16)v1.x, (bf16)v1.y, (bf16)v1.z, (bf16)v1.w };
            *(bf16x8*)&Apk[i] = o;       // 16B store
        }
    } else if (bid < 288) {
        __shared__ bf16 Ts[64 * 72];     // 64n x 64k, pad 8
        const int kt = bid % 12, nt = bid / 12;
        const int k0 = kt * 64, n0 = nt * 64;
        #pragma unroll
        for (int it = 0; it < 4; ++it) {
            const int idx = it * 256 + tid;          // 0..1023
            const int r   = idx >> 4;                // k-row 0..63
            const int c4  = idx & 15;                // n float4 0..15
            float4 v = *(const float4*)&W1[(size_t)(k0 + r) * II + n0 + c4*4];
            Ts[(c4*4 + 0) * 72 + r] = (bf16)v.x;
            Ts[(c4*4 + 1) * 72 + r] = (bf16)v.y;
            Ts[(c4*4 + 2) * 72 + r] = (bf16)v.z;
            Ts[(c4*4 + 3) * 72 + r] = (bf16)v.w;
        }
        __syncthreads();
        #pragma unroll
        for (int it = 0; it < 2; ++it) {
            const int idx = it * 256 + tid;          // 0..511
            const int nr  = idx >> 3;                // n-row 0..63
            const int kc  = idx & 7;                 // k-octet 0..7
            *(bf16x8*)&Wp[(size_t)(n0 + nr) * HH + k0 + kc*8]
                = *(const bf16x8*)&Ts[nr * 72 + kc*8];
        }
    } else if (bid == 288) {
        for (int j = tid; j < II; j += 256)
            gw[j] = gamma[j] * W2[j];
    } else {
        float s1 = 0.f, s2 = 0.f;
        for (int j = tid; j < II; j += 256) {
            float w2 = W2[j];
            s1 += gamma[j] * w2;
            s2 += beta[j]  * w2;
        }
        #pragma unroll
        for (int off = 32; off; off >>= 1) {
            s1 += __shfl_down(s1, off, 64);
            s2 += __shfl_down(s2, off, 64);
        }
        __shared__ float a1[4], a2[4];
        int lane = tid & 63, w = tid >> 6;
        if (lane == 0) { a1[w] = s1; a2[w] = s2; }
        __syncthreads();
        if (tid == 0) {
            scal[0] = a1[0] + a1[1] + a1[2] + a1[3];
            scal[1] = a2[0] + a2[1] + a2[2] + a2[3] + b2[0];
        }
    }
}

// ---------------------------------------------------------------------------
// gemm_part: 128x128 tile, BK=64, 16x16x32 bf16 MFMA, LDS DOUBLE-BUFFERED:
//   top of kt:  vmcnt(0) (covers loads issued a full MFMA phase ago -> ~free)
//               + ONE barrier (publishes cur-buf, closes prev-buf reads)
//   then issue kt+1's global_load_lds into the other buffer, then MFMA.
// Loads stay in flight across the compute phase (AITER pattern) — no full
// drain-before-barrier stall. LDS 64 KB -> 2 blocks/CU.
// Staging layout (per buf): row r, slot g holds k-group g^(r&7) -> lane*16
// contiguity for gld_lds AND <=2-way ds_read_b128 conflicts (free).
// Epilogue: +b1, fast GELU, per-row partial LN stats -> part[s][nb][row].
// ---------------------------------------------------------------------------
__global__ __launch_bounds__(256) void gemm_part(
    const bf16* __restrict__ Apk, const bf16* __restrict__ Wp,
    const float* __restrict__ b1, const float* __restrict__ gw,
    float* __restrict__ part)
{
    __shared__ bf16 As[2 * 128 * 64];      // 32 KB
    __shared__ bf16 Bs[2 * 128 * 64];      // 32 KB

    const int tid  = threadIdx.x;
    // XCD swizzle: 4800 blocks = 8 XCDs x 600; 600 = 50 mb x 12 nb
    const int lin  = (blockIdx.x % 8) * 600 + blockIdx.x / 8;
    const int mb   = lin / 12;
    const int nb   = lin % 12;
    const int lane = tid & 63;
    const int w    = tid >> 6;
    const int wm   = w >> 1;            // 0..1
    const int wn   = w & 1;             // 0..1
    const int m15  = lane & 15;
    const int q    = lane >> 4;         // 0..3
    const int row0 = mb * 128;

    // staging: thread covers row rsub=tid>>3, slot tid&7 (k-group g^(rsub&7))
    const int rsub  = tid >> 3;                   // 0..31
    const int kg    = (tid & 7) ^ (rsub & 7);
    const int lbase = tid * 8;

    const bf16* aP = Apk + (size_t)(row0    + rsub) * HH + kg * 8;
    const bf16* bP = Wp  + (size_t)(nb*128 + rsub) * HH + kg * 8;

    // prologue: issue kt=0 loads into buffer 0
    #pragma unroll
    for (int it = 0; it < 4; ++it) {
        gld_lds16(aP + (size_t)it * 32 * HH, &As[lbase + it * 2048]);
        gld_lds16(bP + (size_t)it * 32 * HH, &Bs[lbase + it * 2048]);
    }

    f32x4 acc[4][4] = {};

    for (int kt = 0; kt < 12; ++kt) {
        const int cur = (kt & 1) * 8192;
        const int nxt = 8192 - cur;

        // cur-buf loads were issued >= one full MFMA phase ago
        asm volatile("s_waitcnt vmcnt(0)" ::: "memory");
        __syncthreads();     // publish cur-buf; close kt-1's reads of nxt-buf

        if (kt < 11) {
            const bf16* aN = aP + (kt + 1) * 64;
            const bf16* bN = bP + (kt + 1) * 64;
            #pragma unroll
            for (int it = 0; it < 4; ++it) {
                gld_lds16(aN + (size_t)it * 32 * HH, &As[nxt + lbase + it * 2048]);
                gld_lds16(bN + (size_t)it * 32 * HH, &Bs[nxt + lbase + it * 2048]);
            }
        }

        #pragma unroll
        for (int kb = 0; kb < 2; ++kb) {
            const int swz = (((kb * 4 + q) ^ (m15 & 7)) * 8);
            bf16x8 af[4], bfr[4];
            #pragma unroll
            for (int mt = 0; mt < 4; ++mt)
                af[mt] = *(const bf16x8*)&As[cur + (wm*64 + mt*16 + m15) * 64 + swz];
            #pragma unroll
            for (int nt = 0; nt < 4; ++nt)
                bfr[nt] = *(const bf16x8*)&Bs[cur + (wn*64 + nt*16 + m15) * 64 + swz];
            #pragma unroll
            for (int mt = 0; mt < 4; ++mt)
                #pragma unroll
                for (int nt = 0; nt < 4; ++nt)
                    acc[mt][nt] = __builtin_amdgcn_mfma_f32_16x16x32_bf16(
                        af[mt], bfr[nt], acc[mt][nt], 0, 0, 0);
        }
    }
    __syncthreads();

    // epilogue: +b1, fast GELU, per-row partial stats over this block's cols
    float* sred = (float*)As;    // As dead; 3 KB reuse

    float bv[4], gv[4];
    #pragma unroll
    for (int nt = 0; nt < 4; ++nt) {
        const int col = nb*128 + wn*64 + nt*16 + m15;
        bv[nt] = b1[col];
        gv[nt] = gw[col];
    }

    #pragma unroll
    for (int mt = 0; mt < 4; ++mt) {
        #pragma unroll
        for (int r = 0; r < 4; ++r) {
            float x0 = 0.f, x1 = 0.f, x2 = 0.f;
            #pragma unroll
            for (int nt = 0; nt < 4; ++nt) {
                // C/D layout: col = lane&15, row = q*4 + r
                float g = fast_gelu(acc[mt][nt][r] + bv[nt]);
                x0 += g; x1 += g * g; x2 += g * gv[nt];
            }
            x0 = red16(x0); x1 = red16(x1); x2 = red16(x2);
            if (m15 == 0) {
                const int rl = wm*64 + mt*16 + q*4 + r;   // 0..127
                sred[wn*384 + rl*3 + 0] = x0;
                sred[wn*384 + rl*3 + 1] = x1;
                sred[wn*384 + rl*3 + 2] = x2;
            }
        }
    }
    __syncthreads();

    if (tid < 128) {
        const size_t rg = (size_t)row0 + tid;
        #pragma unroll
        for (int s = 0; s < 3; ++s)
            part[(size_t)s * 12 * MM + (size_t)nb * MM + rg]
                = sred[0*384 + tid*3 + s] + sred[1*384 + tid*3 + s];
    }
}

// ---------------------------------------------------------------------------
// score_pred: finish LN + sigmoid for the 100 rows of batch b, write scores,
// then pred = sum(scores), logits = one_hot(clamp(round(pred),0,15))
// ---------------------------------------------------------------------------
__global__ __launch_bounds__(128) void score_pred(
    const float* __restrict__ part, const float* __restrict__ scal,
    float* __restrict__ o_scores, float* __restrict__ o_pred,
    float* __restrict__ o_logits)
{
    const int b = blockIdx.x, t = threadIdx.x;
    float s = 0.f;
    if (t < NN) {
        const size_t row = (size_t)b * NN + t;
        float Sh = 0.f, Shh = 0.f, Shg = 0.f;
        #pragma unroll
        for (int j = 0; j < 12; ++j) {
            Sh  += part[(size_t)0*12*MM + (size_t)j*MM + row];
            Shh += part[(size_t)1*12*MM + (size_t)j*MM + row];
            Shg += part[(size_t)2*12*MM + (size_t)j*MM + row];
        }
        const float mu   = Sh * (1.0f / II);
        const float var  = Shh * (1.0f / II) - mu * mu;
        const float rstd = rsqrtf(var + 1e-5f);
        const float z    = rstd * (Shg - mu * scal[0]) + scal[1];
        s = 1.0f / (1.0f + __expf(-z));
        o_scores[row] = s;
    }
    float v = s;
    #pragma unroll
    for (int off = 32; off; off >>= 1) v += __shfl_down(v, off, 64);
    __shared__ float ssum[2];
    const int lane = t & 63, w = t >> 6;
    if (lane == 0) ssum[w] = v;
    __syncthreads();
    const float p = ssum[0] + ssum[1];
    if (t == 0) o_pred[b] = p;
    if (t < 16) {
        int aid = (int)rintf(p);
        aid = aid < 0 ? 0 : (aid > 15 ? 15 : aid);
        o_logits[b * 16 + t] = (t == aid) ? 1.0f : 0.0f;
    }
}

// ---------------------------------------------------------------------------
extern "C" void kernel_launch(void* const* d_in, const int* in_sizes, int n_in,
                              void* d_out, int out_size, void* d_ws, size_t ws_size,
                              hipStream_t stream)
{
    const float* v_emb = (const float*)d_in[0];
    const float* W1    = (const float*)d_in[1];
    const float* b1    = (const float*)d_in[2];
    const float* gamma = (const float*)d_in[3];
    const float* beta  = (const float*)d_in[4];
    const float* W2    = (const float*)d_in[5];
    const float* b2    = (const float*)d_in[6];

    char* ws = (char*)d_ws;
    size_t off = 0;
    bf16*  Wp   = (bf16*)(ws + off);  off += (size_t)II * HH * 2;      // 2.36 MB
    float* gw   = (float*)(ws + off); off += (size_t)II * 4;
    float* scal = (float*)(ws + off); off += 256;
    float* part = (float*)(ws + off); off += (size_t)MM * 36 * 4;      // 7.37 MB
    bf16*  Apk  = (bf16*)(ws + off);  off += (size_t)MM * HH * 2;      // 78.6 MB

    float* out       = (float*)d_out;
    float* o_scores  = out;            // 51200
    float* o_pred    = out + MM;       // 512
    float* o_logits  = out + MM + BB;  // 8192

    hipLaunchKernelGGL(prep_kernel, dim3(290 + 4800), dim3(256), 0, stream,
                       W1, gamma, beta, W2, b2, v_emb, Wp, gw, scal, Apk);
    hipLaunchKernelGGL(gemm_part, dim3((MM / 128) * 12), dim3(256),
                       0, stream, Apk, Wp, b1, gw, part);
    hipLaunchKernelGGL(score_pred, dim3(BB), dim3(128), 0, stream,
                       part, scal, o_scores, o_pred, o_logits);
}